// Round 21
// baseline (110.985 us; speedup 1.0000x reference)
//
#include <hip/hip_runtime.h>

#define EDGES 1600000
#define NN    100000
#define ZD    64
#define FD    16
#define HID   128
#define BM    64          // edges per wave-tile (2 groups of 32)
#define THREADS 256       // 4 waves share one W-table
#define NBLK  768         // persistent: 256 CU x 3 blocks/CU (LDS-limited)
#define NT    25000       // total 64-edge tiles
#define WSTRIDE (NBLK * 4)  // 3072 waves grid-stride over tiles
#define KSTEPS 10         // 9 W1 ksteps + b1 column kstep
#define NFRAG 2560        // 4 blk x 10 ksteps x 64 lanes
#define WT_SHORTS (NFRAG * 8)

typedef __attribute__((ext_vector_type(8)))  short bfrag;   // 8 bf16 = 4 VGPR
typedef __attribute__((ext_vector_type(16))) float f16v;    // 16 f32 acc
typedef __attribute__((ext_vector_type(4)))  float f4v;     // clang vec for NT loads

__device__ __forceinline__ unsigned short f2bf(float f) {
  unsigned u = __builtin_bit_cast(unsigned, f);
  u += 0x7fffu + ((u >> 16) & 1u);   // RNE
  return (unsigned short)(u >> 16);
}
__device__ __forceinline__ unsigned cvtpk(float lo, float hi) {
  unsigned r;
  asm("v_cvt_pk_bf16_f32 %0, %1, %2" : "=v"(r) : "v"(lo), "v"(hi));
  return r;
}
__device__ __forceinline__ void gload16(const void* g, void* l) {
  __builtin_amdgcn_global_load_lds(
      (const __attribute__((address_space(1))) unsigned int*)g,
      (__attribute__((address_space(3))) unsigned int*)l, 16, 0, 0);
}

// z (f32) -> bf16 table in ws
__global__ void zconv_kernel(const float* __restrict__ z,
                             unsigned short* __restrict__ z16, int n4) {
  int i = blockIdx.x * blockDim.x + threadIdx.x;
  if (i >= n4) return;
  float4 f = reinterpret_cast<const float4*>(z)[i];
  ushort4 p;
  p.x = f2bf(f.x); p.y = f2bf(f.y); p.z = f2bf(f.z); p.w = f2bf(f.w);
  reinterpret_cast<ushort4*>(z16)[i] = p;
}

// Pre-swizzled MFMA A-fragment table for W1^T (+ b1 ones-column at k=144).
__global__ void wtab_kernel(const float* __restrict__ W1,
                            const float* __restrict__ b1,
                            unsigned short* __restrict__ WT) {
  int i = blockIdx.x * blockDim.x + threadIdx.x;
  if (i >= WT_SHORTS) return;
  int j    = i & 7;
  int frag = i >> 3;
  int lane = frag & 63;
  int s    = (frag >> 6) % KSTEPS;
  int blk  = frag / (KSTEPS * 64);
  int hid  = blk * 32 + (lane & 31);
  int k    = s * 16 + (lane >> 5) * 8 + j;
  float v = (k < 144) ? W1[k * HID + hid] : (k == 144 ? b1[hid] : 0.f);
  WT[i] = f2bf(v);
}

template<bool ZB>
__global__ __launch_bounds__(THREADS, 2) void fused_kernel(
    const float* __restrict__ zf, const unsigned short* __restrict__ z16,
    const unsigned short* __restrict__ WT,
    const int* __restrict__ ei, const float* __restrict__ ea,
    const float* __restrict__ W2, const float* __restrict__ b2,
    float* __restrict__ out)
{
  __shared__ __align__(16) int4 sW[NFRAG];   // 40 KiB W-fragment table
  __shared__ __align__(16) float sW2[HID];   // 512 B

  const int tid  = threadIdx.x;
  const int lane = tid & 63;
  const int wid  = tid >> 6;       // 0..3
  const int e    = lane & 31;      // edge within group (= MFMA B col = D col)
  const int hi   = lane >> 5;

  // ---- stage W-fragment table + W2 (lane-linear => gload_lds layout ok) ----
  #pragma unroll
  for (int c = 0; c < 10; ++c)
    gload16(WT + (size_t)(c * 256 + tid) * 8, &sW[c * 256 + tid]);
  if (tid < HID) sW2[tid] = W2[tid];
  asm volatile("s_waitcnt vmcnt(0)" ::: "memory");
  __syncthreads();                 // THE ONLY BARRIER

  const float bias2 = b2[0];

  // ones column fragment (k=144 -> 1.0) for the b1 MFMA (pairs with w9)
  int4 oq = {0, 0, 0, 0};
  if (hi == 0) oq.x = 0x3F80;      // bf16 1.0 in element j=0
  const bfrag cone = __builtin_bit_cast(bfrag, oq);

  // persistent zero C-operand
  f16v zerov;
  #pragma unroll
  for (int rg = 0; rg < 16; ++rg) zerov[rg] = 0.f;

  // gather one 32-edge group's 8 z-fragments (cached) + ea (non-temporal)
#define GZ(x0, x1, x2, x3, x4, x5, x6, x7, xa, xb, si, di, ebase) do {         \
    if constexpr (ZB) {                                                        \
      const unsigned short* ps_ = z16 + (size_t)(si) * ZD + hi * 8;            \
      const unsigned short* pd_ = z16 + (size_t)(di) * ZD + hi * 8;            \
      x0 = *reinterpret_cast<const bfrag*>(ps_);                               \
      x1 = *reinterpret_cast<const bfrag*>(ps_ + 16);                          \
      x2 = *reinterpret_cast<const bfrag*>(ps_ + 32);                          \
      x3 = *reinterpret_cast<const bfrag*>(ps_ + 48);                          \
      x4 = *reinterpret_cast<const bfrag*>(pd_);                               \
      x5 = *reinterpret_cast<const bfrag*>(pd_ + 16);                          \
      x6 = *reinterpret_cast<const bfrag*>(pd_ + 32);                          \
      x7 = *reinterpret_cast<const bfrag*>(pd_ + 48);                          \
    } else {                                                                   \
      const float* ps_ = zf + (size_t)(si) * ZD + hi * 8;                      \
      const float* pd_ = zf + (size_t)(di) * ZD + hi * 8;                      \
      float4 a_, b_;                                                           \
      a_ = ((const float4*)ps_)[0]; b_ = ((const float4*)ps_)[1];              \
      { int4 q_ = {(int)cvtpk(a_.x,a_.y),(int)cvtpk(a_.z,a_.w),                \
                   (int)cvtpk(b_.x,b_.y),(int)cvtpk(b_.z,b_.w)};               \
        x0 = __builtin_bit_cast(bfrag, q_); }                                  \
      a_ = ((const float4*)(ps_+16))[0]; b_ = ((const float4*)(ps_+16))[1];    \
      { int4 q_ = {(int)cvtpk(a_.x,a_.y),(int)cvtpk(a_.z,a_.w),                \
                   (int)cvtpk(b_.x,b_.y),(int)cvtpk(b_.z,b_.w)};               \
        x1 = __builtin_bit_cast(bfrag, q_); }                                  \
      a_ = ((const float4*)(ps_+32))[0]; b_ = ((const float4*)(ps_+32))[1];    \
      { int4 q_ = {(int)cvtpk(a_.x,a_.y),(int)cvtpk(a_.z,a_.w),                \
                   (int)cvtpk(b_.x,b_.y),(int)cvtpk(b_.z,b_.w)};               \
        x2 = __builtin_bit_cast(bfrag, q_); }                                  \
      a_ = ((const float4*)(ps_+48))[0]; b_ = ((const float4*)(ps_+48))[1];    \
      { int4 q_ = {(int)cvtpk(a_.x,a_.y),(int)cvtpk(a_.z,a_.w),                \
                   (int)cvtpk(b_.x,b_.y),(int)cvtpk(b_.z,b_.w)};               \
        x3 = __builtin_bit_cast(bfrag, q_); }                                  \
      a_ = ((const float4*)pd_)[0]; b_ = ((const float4*)pd_)[1];              \
      { int4 q_ = {(int)cvtpk(a_.x,a_.y),(int)cvtpk(a_.z,a_.w),                \
                   (int)cvtpk(b_.x,b_.y),(int)cvtpk(b_.z,b_.w)};               \
        x4 = __builtin_bit_cast(bfrag, q_); }                                  \
      a_ = ((const float4*)(pd_+16))[0]; b_ = ((const float4*)(pd_+16))[1];    \
      { int4 q_ = {(int)cvtpk(a_.x,a_.y),(int)cvtpk(a_.z,a_.w),                \
                   (int)cvtpk(b_.x,b_.y),(int)cvtpk(b_.z,b_.w)};               \
        x5 = __builtin_bit_cast(bfrag, q_); }                                  \
      a_ = ((const float4*)(pd_+32))[0]; b_ = ((const float4*)(pd_+32))[1];    \
      { int4 q_ = {(int)cvtpk(a_.x,a_.y),(int)cvtpk(a_.z,a_.w),                \
                   (int)cvtpk(b_.x,b_.y),(int)cvtpk(b_.z,b_.w)};               \
        x6 = __builtin_bit_cast(bfrag, q_); }                                  \
      a_ = ((const float4*)(pd_+48))[0]; b_ = ((const float4*)(pd_+48))[1];    \
      { int4 q_ = {(int)cvtpk(a_.x,a_.y),(int)cvtpk(a_.z,a_.w),                \
                   (int)cvtpk(b_.x,b_.y),(int)cvtpk(b_.z,b_.w)};               \
        x7 = __builtin_bit_cast(bfrag, q_); }                                  \
    }                                                                          \
    const f4v* pe_ = (const f4v*)(ea + (size_t)(ebase) * FD + hi * 8);         \
    xa = __builtin_nontemporal_load(pe_);                                      \
    xb = __builtin_nontemporal_load(pe_ + 1);                                  \
  } while (0)

  // ---- persistent wave-autonomous 64-edge tile loop (grid-stride) ----
  const int gw  = blockIdx.x * 4 + wid;          // global wave id
  const int nit = (NT - 1 - gw) / WSTRIDE + 1;   // 8 or 9 tiles

  int tt0 = gw;
  int sA = __builtin_nontemporal_load(ei + (size_t)tt0 * BM + e);
  int dA = __builtin_nontemporal_load(ei + EDGES + (size_t)tt0 * BM + e);
  int sB = __builtin_nontemporal_load(ei + (size_t)tt0 * BM + 32 + e);
  int dB = __builtin_nontemporal_load(ei + EDGES + (size_t)tt0 * BM + 32 + e);

  for (int t = 0; t < nit; ++t) {
    const int tt = gw + t * WSTRIDE;

    // gather both groups (group-1 latency hides under group-0 compute)
    bfrag a0, a1, a2, a3, a4, a5, a6, a7; f4v aa, ab;
    GZ(a0, a1, a2, a3, a4, a5, a6, a7, aa, ab, sA, dA, (size_t)tt * BM + e);
    bfrag g0, g1, g2, g3, g4, g5, g6, g7; f4v ga, gb;
    GZ(g0, g1, g2, g3, g4, g5, g6, g7, ga, gb, sB, dB, (size_t)tt * BM + 32 + e);

    // prefetch ids for tile t+1 (hidden under compute)
    {
      const int tn = (t + 1 < nit) ? tt + WSTRIDE : tt;
      sA = __builtin_nontemporal_load(ei + (size_t)tn * BM + e);
      dA = __builtin_nontemporal_load(ei + EDGES + (size_t)tn * BM + e);
      sB = __builtin_nontemporal_load(ei + (size_t)tn * BM + 32 + e);
      dB = __builtin_nontemporal_load(ei + EDGES + (size_t)tn * BM + 32 + e);
    }

    // ea fragments (deferred conversion)
    int4 eqa = {(int)cvtpk(aa.x, aa.y), (int)cvtpk(aa.z, aa.w),
                (int)cvtpk(ab.x, ab.y), (int)cvtpk(ab.z, ab.w)};
    bfrag a8 = __builtin_bit_cast(bfrag, eqa);
    int4 eqb = {(int)cvtpk(ga.x, ga.y), (int)cvtpk(ga.z, ga.w),
                (int)cvtpk(gb.x, gb.y), (int)cvtpk(gb.z, gb.w)};
    bfrag g8 = __builtin_bit_cast(bfrag, eqb);

    // ---- 4 hid-blocks; W/W2 reads shared across both edge groups ----
    __builtin_amdgcn_s_setprio(1);
    float p0 = 0.f, p1 = 0.f, p2 = 0.f, p3 = 0.f;   // group 0
    float q0 = 0.f, q1 = 0.f, q2 = 0.f, q3 = 0.f;   // group 1
    #pragma unroll
    for (int blk = 0; blk < 4; ++blk) {
      const int4* wp = &sW[blk * (KSTEPS * 64) + lane];
      bfrag w0 = *reinterpret_cast<const bfrag*>(wp + 0 * 64);
      bfrag w1 = *reinterpret_cast<const bfrag*>(wp + 1 * 64);
      bfrag w2 = *reinterpret_cast<const bfrag*>(wp + 2 * 64);
      bfrag w3 = *reinterpret_cast<const bfrag*>(wp + 3 * 64);
      bfrag w4 = *reinterpret_cast<const bfrag*>(wp + 4 * 64);
      bfrag w5 = *reinterpret_cast<const bfrag*>(wp + 5 * 64);
      bfrag w6 = *reinterpret_cast<const bfrag*>(wp + 6 * 64);
      bfrag w7 = *reinterpret_cast<const bfrag*>(wp + 7 * 64);
      bfrag w8 = *reinterpret_cast<const bfrag*>(wp + 8 * 64);
      bfrag w9 = *reinterpret_cast<const bfrag*>(wp + 9 * 64);

      // group 0: single 10-MFMA chain (b1 cone first)
      f16v accA;
      accA = __builtin_amdgcn_mfma_f32_32x32x16_bf16(w9, cone, zerov, 0, 0, 0);
      accA = __builtin_amdgcn_mfma_f32_32x32x16_bf16(w0, a0, accA, 0, 0, 0);
      accA = __builtin_amdgcn_mfma_f32_32x32x16_bf16(w1, a1, accA, 0, 0, 0);
      accA = __builtin_amdgcn_mfma_f32_32x32x16_bf16(w2, a2, accA, 0, 0, 0);
      accA = __builtin_amdgcn_mfma_f32_32x32x16_bf16(w3, a3, accA, 0, 0, 0);
      accA = __builtin_amdgcn_mfma_f32_32x32x16_bf16(w4, a4, accA, 0, 0, 0);
      accA = __builtin_amdgcn_mfma_f32_32x32x16_bf16(w5, a5, accA, 0, 0, 0);
      accA = __builtin_amdgcn_mfma_f32_32x32x16_bf16(w6, a6, accA, 0, 0, 0);
      accA = __builtin_amdgcn_mfma_f32_32x32x16_bf16(w7, a7, accA, 0, 0, 0);
      accA = __builtin_amdgcn_mfma_f32_32x32x16_bf16(w8, a8, accA, 0, 0, 0);

      // group 1: independent chain (ILP vs group 0)
      f16v accB;
      accB = __builtin_amdgcn_mfma_f32_32x32x16_bf16(w9, cone, zerov, 0, 0, 0);
      accB = __builtin_amdgcn_mfma_f32_32x32x16_bf16(w0, g0, accB, 0, 0, 0);
      accB = __builtin_amdgcn_mfma_f32_32x32x16_bf16(w1, g1, accB, 0, 0, 0);
      accB = __builtin_amdgcn_mfma_f32_32x32x16_bf16(w2, g2, accB, 0, 0, 0);
      accB = __builtin_amdgcn_mfma_f32_32x32x16_bf16(w3, g3, accB, 0, 0, 0);
      accB = __builtin_amdgcn_mfma_f32_32x32x16_bf16(w4, g4, accB, 0, 0, 0);
      accB = __builtin_amdgcn_mfma_f32_32x32x16_bf16(w5, g5, accB, 0, 0, 0);
      accB = __builtin_amdgcn_mfma_f32_32x32x16_bf16(w6, g6, accB, 0, 0, 0);
      accB = __builtin_amdgcn_mfma_f32_32x32x16_bf16(w7, g7, accB, 0, 0, 0);
      accB = __builtin_amdgcn_mfma_f32_32x32x16_bf16(w8, g8, accB, 0, 0, 0);

      // W2 quads from LDS (shared by both groups)
      const float* wq = &sW2[blk * 32 + 4 * hi];
      float4 c0_ = *reinterpret_cast<const float4*>(wq);
      float4 c1_ = *reinterpret_cast<const float4*>(wq + 8);
      float4 c2_ = *reinterpret_cast<const float4*>(wq + 16);
      float4 c3_ = *reinterpret_cast<const float4*>(wq + 24);

      // epilogue (b1 already in acc via cone): ReLU + W2 dot
      p0 = fmaf(fmaxf(accA[0],  0.f), c0_.x, p0);
      p1 = fmaf(fmaxf(accA[1],  0.f), c0_.y, p1);
      p2 = fmaf(fmaxf(accA[2],  0.f), c0_.z, p2);
      p3 = fmaf(fmaxf(accA[3],  0.f), c0_.w, p3);
      p0 = fmaf(fmaxf(accA[4],  0.f), c1_.x, p0);
      p1 = fmaf(fmaxf(accA[5],  0.f), c1_.y, p1);
      p2 = fmaf(fmaxf(accA[6],  0.f), c1_.z, p2);
      p3 = fmaf(fmaxf(accA[7],  0.f), c1_.w, p3);
      p0 = fmaf(fmaxf(accA[8],  0.f), c2_.x, p0);
      p1 = fmaf(fmaxf(accA[9],  0.f), c2_.y, p1);
      p2 = fmaf(fmaxf(accA[10], 0.f), c2_.z, p2);
      p3 = fmaf(fmaxf(accA[11], 0.f), c2_.w, p3);
      p0 = fmaf(fmaxf(accA[12], 0.f), c3_.x, p0);
      p1 = fmaf(fmaxf(accA[13], 0.f), c3_.y, p1);
      p2 = fmaf(fmaxf(accA[14], 0.f), c3_.z, p2);
      p3 = fmaf(fmaxf(accA[15], 0.f), c3_.w, p3);

      q0 = fmaf(fmaxf(accB[0],  0.f), c0_.x, q0);
      q1 = fmaf(fmaxf(accB[1],  0.f), c0_.y, q1);
      q2 = fmaf(fmaxf(accB[2],  0.f), c0_.z, q2);
      q3 = fmaf(fmaxf(accB[3],  0.f), c0_.w, q3);
      q0 = fmaf(fmaxf(accB[4],  0.f), c1_.x, q0);
      q1 = fmaf(fmaxf(accB[5],  0.f), c1_.y, q1);
      q2 = fmaf(fmaxf(accB[6],  0.f), c1_.z, q2);
      q3 = fmaf(fmaxf(accB[7],  0.f), c1_.w, q3);
      q0 = fmaf(fmaxf(accB[8],  0.f), c2_.x, q0);
      q1 = fmaf(fmaxf(accB[9],  0.f), c2_.y, q1);
      q2 = fmaf(fmaxf(accB[10], 0.f), c2_.z, q2);
      q3 = fmaf(fmaxf(accB[11], 0.f), c2_.w, q3);
      q0 = fmaf(fmaxf(accB[12], 0.f), c3_.x, q0);
      q1 = fmaf(fmaxf(accB[13], 0.f), c3_.y, q1);
      q2 = fmaf(fmaxf(accB[14], 0.f), c3_.z, q2);
      q3 = fmaf(fmaxf(accB[15], 0.f), c3_.w, q3);
    }
    __builtin_amdgcn_s_setprio(0);

    float p = (p0 + p1) + (p2 + p3);
    p += __shfl_xor(p, 32);
    float q = (q0 + q1) + (q2 + q3);
    q += __shfl_xor(q, 32);
    if (lane < 32) {
      float vp = 1.f / (1.f + __expf(-(p + bias2)));
      float vq = 1.f / (1.f + __expf(-(q + bias2)));
      __builtin_nontemporal_store(vp, out + (size_t)tt * BM + lane);
      __builtin_nontemporal_store(vq, out + (size_t)tt * BM + 32 + lane);
    }
  }
#undef GZ
}

extern "C" void kernel_launch(void* const* d_in, const int* in_sizes, int n_in,
                              void* d_out, int out_size, void* d_ws, size_t ws_size,
                              hipStream_t stream) {
  const float* z  = (const float*)d_in[0];
  const int*   ei = (const int*)d_in[1];
  const float* ea = (const float*)d_in[2];
  const float* W1 = (const float*)d_in[3];
  const float* b1 = (const float*)d_in[4];
  const float* W2 = (const float*)d_in[5];
  const float* b2 = (const float*)d_in[6];
  float* out = (float*)d_out;

  const size_t z16_bytes = (size_t)NN * ZD * sizeof(unsigned short);
  const size_t wt_bytes  = (size_t)WT_SHORTS * sizeof(unsigned short);

  if (ws_size >= z16_bytes + wt_bytes) {
    unsigned short* z16 = (unsigned short*)d_ws;
    unsigned short* WT  = z16 + (size_t)NN * ZD;
    const int n4 = NN * ZD / 4;
    zconv_kernel<<<(n4 + 255) / 256, 256, 0, stream>>>(z, z16, n4);
    wtab_kernel<<<(WT_SHORTS + 255) / 256, 256, 0, stream>>>(W1, b1, WT);
    fused_kernel<true><<<NBLK, THREADS, 0, stream>>>(
        z, z16, WT, ei, ea, W2, b2, out);
  } else {
    unsigned short* WT = (unsigned short*)d_ws;
    wtab_kernel<<<(WT_SHORTS + 255) / 256, 256, 0, stream>>>(W1, b1, WT);
    fused_kernel<false><<<NBLK, THREADS, 0, stream>>>(
        z, nullptr, WT, ei, ea, W2, b2, out);
  }
}

// Round 22
// 107.500 us; speedup vs baseline: 1.0324x; 1.0324x over previous
//
#include <hip/hip_runtime.h>

#define EDGES 1600000
#define NN    100000
#define ZD    64
#define FD    16
#define HID   128
#define BM    64          // edges per wave-tile (2 groups of 32)
#define THREADS 256       // 4 waves share one W-table
#define NBLK  768         // persistent: 256 CU x 3 blocks/CU (LDS-limited)
#define NT    25000       // total 64-edge tiles
#define WSTRIDE (NBLK * 4)  // 3072 waves grid-stride over tiles
#define KSTEPS 10         // 9 W1 ksteps + b1 column kstep
#define NFRAG 2560        // 4 blk x 10 ksteps x 64 lanes
#define WT_SHORTS (NFRAG * 8)

typedef __attribute__((ext_vector_type(8)))  short bfrag;   // 8 bf16 = 4 VGPR
typedef __attribute__((ext_vector_type(16))) float f16v;    // 16 f32 acc

__device__ __forceinline__ unsigned short f2bf(float f) {
  unsigned u = __builtin_bit_cast(unsigned, f);
  u += 0x7fffu + ((u >> 16) & 1u);   // RNE
  return (unsigned short)(u >> 16);
}
__device__ __forceinline__ unsigned cvtpk(float lo, float hi) {
  unsigned r;
  asm("v_cvt_pk_bf16_f32 %0, %1, %2" : "=v"(r) : "v"(lo), "v"(hi));
  return r;
}
__device__ __forceinline__ void gload16(const void* g, void* l) {
  __builtin_amdgcn_global_load_lds(
      (const __attribute__((address_space(1))) unsigned int*)g,
      (__attribute__((address_space(3))) unsigned int*)l, 16, 0, 0);
}

// z (f32) -> bf16 table in ws
__global__ void zconv_kernel(const float* __restrict__ z,
                             unsigned short* __restrict__ z16, int n4) {
  int i = blockIdx.x * blockDim.x + threadIdx.x;
  if (i >= n4) return;
  float4 f = reinterpret_cast<const float4*>(z)[i];
  ushort4 p;
  p.x = f2bf(f.x); p.y = f2bf(f.y); p.z = f2bf(f.z); p.w = f2bf(f.w);
  reinterpret_cast<ushort4*>(z16)[i] = p;
}

// Pre-swizzled MFMA A-fragment table for W1^T (+ b1 ones-column at k=144).
__global__ void wtab_kernel(const float* __restrict__ W1,
                            const float* __restrict__ b1,
                            unsigned short* __restrict__ WT) {
  int i = blockIdx.x * blockDim.x + threadIdx.x;
  if (i >= WT_SHORTS) return;
  int j    = i & 7;
  int frag = i >> 3;
  int lane = frag & 63;
  int s    = (frag >> 6) % KSTEPS;
  int blk  = frag / (KSTEPS * 64);
  int hid  = blk * 32 + (lane & 31);
  int k    = s * 16 + (lane >> 5) * 8 + j;
  float v = (k < 144) ? W1[k * HID + hid] : (k == 144 ? b1[hid] : 0.f);
  WT[i] = f2bf(v);
}

template<bool ZB>
__global__ __launch_bounds__(THREADS, 2) void fused_kernel(
    const float* __restrict__ zf, const unsigned short* __restrict__ z16,
    const unsigned short* __restrict__ WT,
    const int* __restrict__ ei, const float* __restrict__ ea,
    const float* __restrict__ W2, const float* __restrict__ b2,
    float* __restrict__ out)
{
  __shared__ __align__(16) int4 sW[NFRAG];   // 40 KiB W-fragment table
  __shared__ __align__(16) float sW2[HID];   // 512 B

  const int tid  = threadIdx.x;
  const int lane = tid & 63;
  const int wid  = tid >> 6;       // 0..3
  const int e    = lane & 31;      // edge within group (= MFMA B col = D col)
  const int hi   = lane >> 5;

  // ---- stage W-fragment table + W2 (lane-linear => gload_lds layout ok) ----
  #pragma unroll
  for (int c = 0; c < 10; ++c)
    gload16(WT + (size_t)(c * 256 + tid) * 8, &sW[c * 256 + tid]);
  if (tid < HID) sW2[tid] = W2[tid];
  asm volatile("s_waitcnt vmcnt(0)" ::: "memory");
  __syncthreads();                 // THE ONLY BARRIER

  const float bias2 = b2[0];

  // ones column fragment (k=144 -> 1.0) for the b1 MFMA (pairs with w9)
  int4 oq = {0, 0, 0, 0};
  if (hi == 0) oq.x = 0x3F80;      // bf16 1.0 in element j=0
  const bfrag cone = __builtin_bit_cast(bfrag, oq);

  // persistent zero C-operand
  f16v zerov;
  #pragma unroll
  for (int rg = 0; rg < 16; ++rg) zerov[rg] = 0.f;

  // gather one 32-edge group's 8 z-fragments + raw ea float4s (cvtpk deferred)
#define GZ(x0, x1, x2, x3, x4, x5, x6, x7, xa, xb, si, di, ebase) do {         \
    if constexpr (ZB) {                                                        \
      const unsigned short* ps_ = z16 + (size_t)(si) * ZD + hi * 8;            \
      const unsigned short* pd_ = z16 + (size_t)(di) * ZD + hi * 8;            \
      x0 = *reinterpret_cast<const bfrag*>(ps_);                               \
      x1 = *reinterpret_cast<const bfrag*>(ps_ + 16);                          \
      x2 = *reinterpret_cast<const bfrag*>(ps_ + 32);                          \
      x3 = *reinterpret_cast<const bfrag*>(ps_ + 48);                          \
      x4 = *reinterpret_cast<const bfrag*>(pd_);                               \
      x5 = *reinterpret_cast<const bfrag*>(pd_ + 16);                          \
      x6 = *reinterpret_cast<const bfrag*>(pd_ + 32);                          \
      x7 = *reinterpret_cast<const bfrag*>(pd_ + 48);                          \
    } else {                                                                   \
      const float* ps_ = zf + (size_t)(si) * ZD + hi * 8;                      \
      const float* pd_ = zf + (size_t)(di) * ZD + hi * 8;                      \
      float4 a_, b_;                                                           \
      a_ = ((const float4*)ps_)[0]; b_ = ((const float4*)ps_)[1];              \
      { int4 q_ = {(int)cvtpk(a_.x,a_.y),(int)cvtpk(a_.z,a_.w),                \
                   (int)cvtpk(b_.x,b_.y),(int)cvtpk(b_.z,b_.w)};               \
        x0 = __builtin_bit_cast(bfrag, q_); }                                  \
      a_ = ((const float4*)(ps_+16))[0]; b_ = ((const float4*)(ps_+16))[1];    \
      { int4 q_ = {(int)cvtpk(a_.x,a_.y),(int)cvtpk(a_.z,a_.w),                \
                   (int)cvtpk(b_.x,b_.y),(int)cvtpk(b_.z,b_.w)};               \
        x1 = __builtin_bit_cast(bfrag, q_); }                                  \
      a_ = ((const float4*)(ps_+32))[0]; b_ = ((const float4*)(ps_+32))[1];    \
      { int4 q_ = {(int)cvtpk(a_.x,a_.y),(int)cvtpk(a_.z,a_.w),                \
                   (int)cvtpk(b_.x,b_.y),(int)cvtpk(b_.z,b_.w)};               \
        x2 = __builtin_bit_cast(bfrag, q_); }                                  \
      a_ = ((const float4*)(ps_+48))[0]; b_ = ((const float4*)(ps_+48))[1];    \
      { int4 q_ = {(int)cvtpk(a_.x,a_.y),(int)cvtpk(a_.z,a_.w),                \
                   (int)cvtpk(b_.x,b_.y),(int)cvtpk(b_.z,b_.w)};               \
        x3 = __builtin_bit_cast(bfrag, q_); }                                  \
      a_ = ((const float4*)pd_)[0]; b_ = ((const float4*)pd_)[1];              \
      { int4 q_ = {(int)cvtpk(a_.x,a_.y),(int)cvtpk(a_.z,a_.w),                \
                   (int)cvtpk(b_.x,b_.y),(int)cvtpk(b_.z,b_.w)};               \
        x4 = __builtin_bit_cast(bfrag, q_); }                                  \
      a_ = ((const float4*)(pd_+16))[0]; b_ = ((const float4*)(pd_+16))[1];    \
      { int4 q_ = {(int)cvtpk(a_.x,a_.y),(int)cvtpk(a_.z,a_.w),                \
                   (int)cvtpk(b_.x,b_.y),(int)cvtpk(b_.z,b_.w)};               \
        x5 = __builtin_bit_cast(bfrag, q_); }                                  \
      a_ = ((const float4*)(pd_+32))[0]; b_ = ((const float4*)(pd_+32))[1];    \
      { int4 q_ = {(int)cvtpk(a_.x,a_.y),(int)cvtpk(a_.z,a_.w),                \
                   (int)cvtpk(b_.x,b_.y),(int)cvtpk(b_.z,b_.w)};               \
        x6 = __builtin_bit_cast(bfrag, q_); }                                  \
      a_ = ((const float4*)(pd_+48))[0]; b_ = ((const float4*)(pd_+48))[1];    \
      { int4 q_ = {(int)cvtpk(a_.x,a_.y),(int)cvtpk(a_.z,a_.w),                \
                   (int)cvtpk(b_.x,b_.y),(int)cvtpk(b_.z,b_.w)};               \
        x7 = __builtin_bit_cast(bfrag, q_); }                                  \
    }                                                                          \
    const float* pe_ = ea + (size_t)(ebase) * FD + hi * 8;                     \
    xa = ((const float4*)pe_)[0];                                              \
    xb = ((const float4*)pe_)[1];                                              \
  } while (0)

  // ---- persistent wave-autonomous 64-edge tile loop (grid-stride) ----
  const int gw  = blockIdx.x * 4 + wid;          // global wave id
  const int nit = (NT - 1 - gw) / WSTRIDE + 1;   // 8 or 9 tiles

  int tt0 = gw;
  int sA = ei[(size_t)tt0 * BM + e];
  int dA = ei[EDGES + (size_t)tt0 * BM + e];
  int sB = ei[(size_t)tt0 * BM + 32 + e];
  int dB = ei[EDGES + (size_t)tt0 * BM + 32 + e];

  for (int t = 0; t < nit; ++t) {
    const int tt = gw + t * WSTRIDE;

    // gather both groups (group-1 latency hides under group-0 compute)
    bfrag a0, a1, a2, a3, a4, a5, a6, a7; float4 aa, ab;
    GZ(a0, a1, a2, a3, a4, a5, a6, a7, aa, ab, sA, dA, (size_t)tt * BM + e);
    bfrag g0, g1, g2, g3, g4, g5, g6, g7; float4 ga, gb;
    GZ(g0, g1, g2, g3, g4, g5, g6, g7, ga, gb, sB, dB, (size_t)tt * BM + 32 + e);

    // prefetch ids for tile t+1 (hidden under compute)
    {
      const int tn = (t + 1 < nit) ? tt + WSTRIDE : tt;
      sA = ei[(size_t)tn * BM + e];
      dA = ei[EDGES + (size_t)tn * BM + e];
      sB = ei[(size_t)tn * BM + 32 + e];
      dB = ei[EDGES + (size_t)tn * BM + 32 + e];
    }

    // ea fragments (deferred conversion)
    int4 eqa = {(int)cvtpk(aa.x, aa.y), (int)cvtpk(aa.z, aa.w),
                (int)cvtpk(ab.x, ab.y), (int)cvtpk(ab.z, ab.w)};
    bfrag a8 = __builtin_bit_cast(bfrag, eqa);
    int4 eqb = {(int)cvtpk(ga.x, ga.y), (int)cvtpk(ga.z, ga.w),
                (int)cvtpk(gb.x, gb.y), (int)cvtpk(gb.z, gb.w)};
    bfrag g8 = __builtin_bit_cast(bfrag, eqb);

    // ---- 4 hid-blocks; W/W2 reads shared across both edge groups ----
    __builtin_amdgcn_s_setprio(1);
    float p0 = 0.f, p1 = 0.f, p2 = 0.f, p3 = 0.f;   // group 0
    float q0 = 0.f, q1 = 0.f, q2 = 0.f, q3 = 0.f;   // group 1
    #pragma unroll
    for (int blk = 0; blk < 4; ++blk) {
      const int4* wp = &sW[blk * (KSTEPS * 64) + lane];
      bfrag w0 = *reinterpret_cast<const bfrag*>(wp + 0 * 64);
      bfrag w1 = *reinterpret_cast<const bfrag*>(wp + 1 * 64);
      bfrag w2 = *reinterpret_cast<const bfrag*>(wp + 2 * 64);
      bfrag w3 = *reinterpret_cast<const bfrag*>(wp + 3 * 64);
      bfrag w4 = *reinterpret_cast<const bfrag*>(wp + 4 * 64);
      bfrag w5 = *reinterpret_cast<const bfrag*>(wp + 5 * 64);
      bfrag w6 = *reinterpret_cast<const bfrag*>(wp + 6 * 64);
      bfrag w7 = *reinterpret_cast<const bfrag*>(wp + 7 * 64);
      bfrag w8 = *reinterpret_cast<const bfrag*>(wp + 8 * 64);
      bfrag w9 = *reinterpret_cast<const bfrag*>(wp + 9 * 64);

      // group 0: single 10-MFMA chain (b1 cone first)
      f16v accA;
      accA = __builtin_amdgcn_mfma_f32_32x32x16_bf16(w9, cone, zerov, 0, 0, 0);
      accA = __builtin_amdgcn_mfma_f32_32x32x16_bf16(w0, a0, accA, 0, 0, 0);
      accA = __builtin_amdgcn_mfma_f32_32x32x16_bf16(w1, a1, accA, 0, 0, 0);
      accA = __builtin_amdgcn_mfma_f32_32x32x16_bf16(w2, a2, accA, 0, 0, 0);
      accA = __builtin_amdgcn_mfma_f32_32x32x16_bf16(w3, a3, accA, 0, 0, 0);
      accA = __builtin_amdgcn_mfma_f32_32x32x16_bf16(w4, a4, accA, 0, 0, 0);
      accA = __builtin_amdgcn_mfma_f32_32x32x16_bf16(w5, a5, accA, 0, 0, 0);
      accA = __builtin_amdgcn_mfma_f32_32x32x16_bf16(w6, a6, accA, 0, 0, 0);
      accA = __builtin_amdgcn_mfma_f32_32x32x16_bf16(w7, a7, accA, 0, 0, 0);
      accA = __builtin_amdgcn_mfma_f32_32x32x16_bf16(w8, a8, accA, 0, 0, 0);

      // group 1: independent chain (ILP vs group 0)
      f16v accB;
      accB = __builtin_amdgcn_mfma_f32_32x32x16_bf16(w9, cone, zerov, 0, 0, 0);
      accB = __builtin_amdgcn_mfma_f32_32x32x16_bf16(w0, g0, accB, 0, 0, 0);
      accB = __builtin_amdgcn_mfma_f32_32x32x16_bf16(w1, g1, accB, 0, 0, 0);
      accB = __builtin_amdgcn_mfma_f32_32x32x16_bf16(w2, g2, accB, 0, 0, 0);
      accB = __builtin_amdgcn_mfma_f32_32x32x16_bf16(w3, g3, accB, 0, 0, 0);
      accB = __builtin_amdgcn_mfma_f32_32x32x16_bf16(w4, g4, accB, 0, 0, 0);
      accB = __builtin_amdgcn_mfma_f32_32x32x16_bf16(w5, g5, accB, 0, 0, 0);
      accB = __builtin_amdgcn_mfma_f32_32x32x16_bf16(w6, g6, accB, 0, 0, 0);
      accB = __builtin_amdgcn_mfma_f32_32x32x16_bf16(w7, g7, accB, 0, 0, 0);
      accB = __builtin_amdgcn_mfma_f32_32x32x16_bf16(w8, g8, accB, 0, 0, 0);

      // W2 quads from LDS (shared by both groups)
      const float* wq = &sW2[blk * 32 + 4 * hi];
      float4 c0_ = *reinterpret_cast<const float4*>(wq);
      float4 c1_ = *reinterpret_cast<const float4*>(wq + 8);
      float4 c2_ = *reinterpret_cast<const float4*>(wq + 16);
      float4 c3_ = *reinterpret_cast<const float4*>(wq + 24);

      // epilogue (b1 already in acc via cone): ReLU + W2 dot
      p0 = fmaf(fmaxf(accA[0],  0.f), c0_.x, p0);
      p1 = fmaf(fmaxf(accA[1],  0.f), c0_.y, p1);
      p2 = fmaf(fmaxf(accA[2],  0.f), c0_.z, p2);
      p3 = fmaf(fmaxf(accA[3],  0.f), c0_.w, p3);
      p0 = fmaf(fmaxf(accA[4],  0.f), c1_.x, p0);
      p1 = fmaf(fmaxf(accA[5],  0.f), c1_.y, p1);
      p2 = fmaf(fmaxf(accA[6],  0.f), c1_.z, p2);
      p3 = fmaf(fmaxf(accA[7],  0.f), c1_.w, p3);
      p0 = fmaf(fmaxf(accA[8],  0.f), c2_.x, p0);
      p1 = fmaf(fmaxf(accA[9],  0.f), c2_.y, p1);
      p2 = fmaf(fmaxf(accA[10], 0.f), c2_.z, p2);
      p3 = fmaf(fmaxf(accA[11], 0.f), c2_.w, p3);
      p0 = fmaf(fmaxf(accA[12], 0.f), c3_.x, p0);
      p1 = fmaf(fmaxf(accA[13], 0.f), c3_.y, p1);
      p2 = fmaf(fmaxf(accA[14], 0.f), c3_.z, p2);
      p3 = fmaf(fmaxf(accA[15], 0.f), c3_.w, p3);

      q0 = fmaf(fmaxf(accB[0],  0.f), c0_.x, q0);
      q1 = fmaf(fmaxf(accB[1],  0.f), c0_.y, q1);
      q2 = fmaf(fmaxf(accB[2],  0.f), c0_.z, q2);
      q3 = fmaf(fmaxf(accB[3],  0.f), c0_.w, q3);
      q0 = fmaf(fmaxf(accB[4],  0.f), c1_.x, q0);
      q1 = fmaf(fmaxf(accB[5],  0.f), c1_.y, q1);
      q2 = fmaf(fmaxf(accB[6],  0.f), c1_.z, q2);
      q3 = fmaf(fmaxf(accB[7],  0.f), c1_.w, q3);
      q0 = fmaf(fmaxf(accB[8],  0.f), c2_.x, q0);
      q1 = fmaf(fmaxf(accB[9],  0.f), c2_.y, q1);
      q2 = fmaf(fmaxf(accB[10], 0.f), c2_.z, q2);
      q3 = fmaf(fmaxf(accB[11], 0.f), c2_.w, q3);
      q0 = fmaf(fmaxf(accB[12], 0.f), c3_.x, q0);
      q1 = fmaf(fmaxf(accB[13], 0.f), c3_.y, q1);
      q2 = fmaf(fmaxf(accB[14], 0.f), c3_.z, q2);
      q3 = fmaf(fmaxf(accB[15], 0.f), c3_.w, q3);
    }
    __builtin_amdgcn_s_setprio(0);

    float p = (p0 + p1) + (p2 + p3);
    p += __shfl_xor(p, 32);
    float q = (q0 + q1) + (q2 + q3);
    q += __shfl_xor(q, 32);
    if (lane < 32) {
      float vp = 1.f / (1.f + __expf(-(p + bias2)));
      float vq = 1.f / (1.f + __expf(-(q + bias2)));
      __builtin_nontemporal_store(vp, out + (size_t)tt * BM + lane);
      __builtin_nontemporal_store(vq, out + (size_t)tt * BM + 32 + lane);
    }
  }
#undef GZ
}

extern "C" void kernel_launch(void* const* d_in, const int* in_sizes, int n_in,
                              void* d_out, int out_size, void* d_ws, size_t ws_size,
                              hipStream_t stream) {
  const float* z  = (const float*)d_in[0];
  const int*   ei = (const int*)d_in[1];
  const float* ea = (const float*)d_in[2];
  const float* W1 = (const float*)d_in[3];
  const float* b1 = (const float*)d_in[4];
  const float* W2 = (const float*)d_in[5];
  const float* b2 = (const float*)d_in[6];
  float* out = (float*)d_out;

  const size_t z16_bytes = (size_t)NN * ZD * sizeof(unsigned short);
  const size_t wt_bytes  = (size_t)WT_SHORTS * sizeof(unsigned short);

  if (ws_size >= z16_bytes + wt_bytes) {
    unsigned short* z16 = (unsigned short*)d_ws;
    unsigned short* WT  = z16 + (size_t)NN * ZD;
    const int n4 = NN * ZD / 4;
    zconv_kernel<<<(n4 + 255) / 256, 256, 0, stream>>>(z, z16, n4);
    wtab_kernel<<<(WT_SHORTS + 255) / 256, 256, 0, stream>>>(W1, b1, WT);
    fused_kernel<true><<<NBLK, THREADS, 0, stream>>>(
        z, z16, WT, ei, ea, W2, b2, out);
  } else {
    unsigned short* WT = (unsigned short*)d_ws;
    wtab_kernel<<<(WT_SHORTS + 255) / 256, 256, 0, stream>>>(W1, b1, WT);
    fused_kernel<false><<<NBLK, THREADS, 0, stream>>>(
        z, nullptr, WT, ei, ea, W2, b2, out);
  }
}

// Round 23
// 91.333 us; speedup vs baseline: 1.2152x; 1.1770x over previous
//
#include <hip/hip_runtime.h>

#define EDGES 1600000
#define NN    100000
#define ZD    64
#define FD    16
#define HID   128
#define BM    32          // edges per wave-tile
#define THREADS 256       // 4 waves share one W-table
#define NBLK  768         // persistent: 256 CU x 3 blocks/CU resident
#define NT    50000       // total tiles
#define WSTRIDE (NBLK * 4)  // 3072 waves, grid-stride over tiles
#define NFRAG 2560        // 4 blk x 10 ksteps x 64 lanes
#define WT_SHORTS (NFRAG * 8)

typedef __attribute__((ext_vector_type(8)))  short bfrag;   // 8 bf16 = 4 VGPR
typedef __attribute__((ext_vector_type(16))) float f16v;    // 16 f32 acc

__device__ __forceinline__ unsigned short f2bf(float f) {
  unsigned u = __builtin_bit_cast(unsigned, f);
  u += 0x7fffu + ((u >> 16) & 1u);   // RNE
  return (unsigned short)(u >> 16);
}
__device__ __forceinline__ unsigned cvtpk(float lo, float hi) {
  unsigned r;
  asm("v_cvt_pk_bf16_f32 %0, %1, %2" : "=v"(r) : "v"(lo), "v"(hi));
  return r;
}
__device__ __forceinline__ void gload16(const void* g, void* l) {
  __builtin_amdgcn_global_load_lds(
      (const __attribute__((address_space(1))) unsigned int*)g,
      (__attribute__((address_space(3))) unsigned int*)l, 16, 0, 0);
}

// z (f32) -> bf16 table in ws
__global__ void zconv_kernel(const float* __restrict__ z,
                             unsigned short* __restrict__ z16, int n4) {
  int i = blockIdx.x * blockDim.x + threadIdx.x;
  if (i >= n4) return;
  float4 f = reinterpret_cast<const float4*>(z)[i];
  ushort4 p;
  p.x = f2bf(f.x); p.y = f2bf(f.y); p.z = f2bf(f.z); p.w = f2bf(f.w);
  reinterpret_cast<ushort4*>(z16)[i] = p;
}

// Pre-swizzled MFMA A-fragment table for W1^T (+ b1 ones-column at k=144).
__global__ void wtab_kernel(const float* __restrict__ W1,
                            const float* __restrict__ b1,
                            unsigned short* __restrict__ WT) {
  int i = blockIdx.x * blockDim.x + threadIdx.x;
  if (i >= WT_SHORTS) return;
  int j    = i & 7;
  int frag = i >> 3;
  int lane = frag & 63;
  int s    = (frag >> 6) % 10;
  int blk  = frag / 640;
  int hid  = blk * 32 + (lane & 31);
  int k    = s * 16 + (lane >> 5) * 8 + j;
  float v = (k < 144) ? W1[k * HID + hid] : (k == 144 ? b1[hid] : 0.f);
  WT[i] = f2bf(v);
}

template<bool ZB>
__global__ __launch_bounds__(THREADS, 2) void fused_kernel(
    const float* __restrict__ zf, const unsigned short* __restrict__ z16,
    const unsigned short* __restrict__ WT,
    const int* __restrict__ ei, const float* __restrict__ ea,
    const float* __restrict__ W2, const float* __restrict__ b2,
    float* __restrict__ out)
{
  __shared__ __align__(16) int4 sW[NFRAG];   // 40 KiB W-fragment table
  __shared__ __align__(16) float sW2[HID];   // 512 B

  const int tid  = threadIdx.x;
  const int lane = tid & 63;
  const int wid  = tid >> 6;       // 0..3
  const int e    = lane & 31;      // edge within tile (= MFMA B col = D col)
  const int hi   = lane >> 5;

  // ---- stage W-fragment table + W2 (lane-linear => gload_lds layout ok) ----
  #pragma unroll
  for (int c = 0; c < 10; ++c)
    gload16(WT + (size_t)(c * 256 + tid) * 8, &sW[c * 256 + tid]);
  if (tid < HID) sW2[tid] = W2[tid];
  asm volatile("s_waitcnt vmcnt(0)" ::: "memory");
  __syncthreads();                 // THE ONLY BARRIER

  const float bias2 = b2[0];

  // ones column fragment (k=144 -> 1.0) for the b1 MFMA (pairs with w9)
  int4 oq = {0, 0, 0, 0};
  if (hi == 0) oq.x = 0x3F80;      // bf16 1.0 in element j=0
  const bfrag cone = __builtin_bit_cast(bfrag, oq);

  // persistent zero C-operand
  f16v zerov;
  #pragma unroll
  for (int rg = 0; rg < 16; ++rg) zerov[rg] = 0.f;

  // gather one tile's 8 z-fragments + raw ea float4s (cvtpk deferred)
#define GZ(x0, x1, x2, x3, x4, x5, x6, x7, xa, xb, si, di, tt) do {            \
    if constexpr (ZB) {                                                        \
      const unsigned short* ps_ = z16 + (size_t)(si) * ZD + hi * 8;            \
      const unsigned short* pd_ = z16 + (size_t)(di) * ZD + hi * 8;            \
      x0 = *reinterpret_cast<const bfrag*>(ps_);                               \
      x1 = *reinterpret_cast<const bfrag*>(ps_ + 16);                          \
      x2 = *reinterpret_cast<const bfrag*>(ps_ + 32);                          \
      x3 = *reinterpret_cast<const bfrag*>(ps_ + 48);                          \
      x4 = *reinterpret_cast<const bfrag*>(pd_);                               \
      x5 = *reinterpret_cast<const bfrag*>(pd_ + 16);                          \
      x6 = *reinterpret_cast<const bfrag*>(pd_ + 32);                          \
      x7 = *reinterpret_cast<const bfrag*>(pd_ + 48);                          \
    } else {                                                                   \
      const float* ps_ = zf + (size_t)(si) * ZD + hi * 8;                      \
      const float* pd_ = zf + (size_t)(di) * ZD + hi * 8;                      \
      float4 a_, b_;                                                           \
      a_ = ((const float4*)ps_)[0]; b_ = ((const float4*)ps_)[1];              \
      { int4 q_ = {(int)cvtpk(a_.x,a_.y),(int)cvtpk(a_.z,a_.w),                \
                   (int)cvtpk(b_.x,b_.y),(int)cvtpk(b_.z,b_.w)};               \
        x0 = __builtin_bit_cast(bfrag, q_); }                                  \
      a_ = ((const float4*)(ps_+16))[0]; b_ = ((const float4*)(ps_+16))[1];    \
      { int4 q_ = {(int)cvtpk(a_.x,a_.y),(int)cvtpk(a_.z,a_.w),                \
                   (int)cvtpk(b_.x,b_.y),(int)cvtpk(b_.z,b_.w)};               \
        x1 = __builtin_bit_cast(bfrag, q_); }                                  \
      a_ = ((const float4*)(ps_+32))[0]; b_ = ((const float4*)(ps_+32))[1];    \
      { int4 q_ = {(int)cvtpk(a_.x,a_.y),(int)cvtpk(a_.z,a_.w),                \
                   (int)cvtpk(b_.x,b_.y),(int)cvtpk(b_.z,b_.w)};               \
        x2 = __builtin_bit_cast(bfrag, q_); }                                  \
      a_ = ((const float4*)(ps_+48))[0]; b_ = ((const float4*)(ps_+48))[1];    \
      { int4 q_ = {(int)cvtpk(a_.x,a_.y),(int)cvtpk(a_.z,a_.w),                \
                   (int)cvtpk(b_.x,b_.y),(int)cvtpk(b_.z,b_.w)};               \
        x3 = __builtin_bit_cast(bfrag, q_); }                                  \
      a_ = ((const float4*)pd_)[0]; b_ = ((const float4*)pd_)[1];              \
      { int4 q_ = {(int)cvtpk(a_.x,a_.y),(int)cvtpk(a_.z,a_.w),                \
                   (int)cvtpk(b_.x,b_.y),(int)cvtpk(b_.z,b_.w)};               \
        x4 = __builtin_bit_cast(bfrag, q_); }                                  \
      a_ = ((const float4*)(pd_+16))[0]; b_ = ((const float4*)(pd_+16))[1];    \
      { int4 q_ = {(int)cvtpk(a_.x,a_.y),(int)cvtpk(a_.z,a_.w),                \
                   (int)cvtpk(b_.x,b_.y),(int)cvtpk(b_.z,b_.w)};               \
        x5 = __builtin_bit_cast(bfrag, q_); }                                  \
      a_ = ((const float4*)(pd_+32))[0]; b_ = ((const float4*)(pd_+32))[1];    \
      { int4 q_ = {(int)cvtpk(a_.x,a_.y),(int)cvtpk(a_.z,a_.w),                \
                   (int)cvtpk(b_.x,b_.y),(int)cvtpk(b_.z,b_.w)};               \
        x6 = __builtin_bit_cast(bfrag, q_); }                                  \
      a_ = ((const float4*)(pd_+48))[0]; b_ = ((const float4*)(pd_+48))[1];    \
      { int4 q_ = {(int)cvtpk(a_.x,a_.y),(int)cvtpk(a_.z,a_.w),                \
                   (int)cvtpk(b_.x,b_.y),(int)cvtpk(b_.z,b_.w)};               \
        x7 = __builtin_bit_cast(bfrag, q_); }                                  \
    }                                                                          \
    const float* pe_ = ea + ((size_t)(tt) * BM + e) * FD + hi * 8;             \
    xa = ((const float4*)pe_)[0];                                              \
    xb = ((const float4*)pe_)[1];                                              \
  } while (0)

  // ---- persistent wave-autonomous tile loop (grid-stride) ----
  const int gw  = blockIdx.x * 4 + wid;              // global wave id
  const int nit = (NT - 1 - gw) / WSTRIDE + 1;       // 16 or 17 tiles

  int tt0 = gw;
  int si = ei[(size_t)tt0 * BM + e];
  int di = ei[(size_t)EDGES + (size_t)tt0 * BM + e];
  bfrag c0, c1, c2, c3, c4, c5, c6, c7; float4 ca, cb;
  GZ(c0, c1, c2, c3, c4, c5, c6, c7, ca, cb, si, di, tt0);
  int t1 = (nit > 1) ? gw + WSTRIDE : tt0;
  int s1 = ei[(size_t)t1 * BM + e];
  int d1 = ei[(size_t)EDGES + (size_t)t1 * BM + e];

  for (int t = 0; t < nit; ++t) {
    const int tt = gw + t * WSTRIDE;

    // issue next tile's gathers (consumed next iteration)
    const int kn = (t + 1 < nit) ? t + 1 : nit - 1;
    const int tn = gw + kn * WSTRIDE;
    bfrag n0, n1, n2, n3, n4, n5, n6, n7; float4 na, nb;
    GZ(n0, n1, n2, n3, n4, n5, n6, n7, na, nb, s1, d1, tn);

    // ids 2 tiles ahead
    const int kf = (t + 2 < nit) ? t + 2 : nit - 1;
    const int tf = gw + kf * WSTRIDE;
    s1 = ei[(size_t)tf * BM + e];
    d1 = ei[(size_t)EDGES + (size_t)tf * BM + e];

    // build current ea fragment (deferred conversion)
    int4 eq = {(int)cvtpk(ca.x, ca.y), (int)cvtpk(ca.z, ca.w),
               (int)cvtpk(cb.x, cb.y), (int)cvtpk(cb.z, cb.w)};
    bfrag c8 = __builtin_bit_cast(bfrag, eq);

    // ---- 4 hid-blocks; per blk: two 5-deep MFMA chains, W from LDS ----
    __builtin_amdgcn_s_setprio(1);
    float p0 = 0.f, p1 = 0.f, p2 = 0.f, p3 = 0.f;
    #pragma unroll
    for (int blk = 0; blk < 4; ++blk) {
      const int4* wp = &sW[blk * 640 + lane];

      // chain A (even ksteps + ea)
      bfrag w0 = *reinterpret_cast<const bfrag*>(wp + 0 * 64);
      bfrag w2 = *reinterpret_cast<const bfrag*>(wp + 2 * 64);
      bfrag w4 = *reinterpret_cast<const bfrag*>(wp + 4 * 64);
      bfrag w6 = *reinterpret_cast<const bfrag*>(wp + 6 * 64);
      bfrag w8 = *reinterpret_cast<const bfrag*>(wp + 8 * 64);
      f16v accA;
      accA = __builtin_amdgcn_mfma_f32_32x32x16_bf16(w0, c0, zerov, 0, 0, 0);
      accA = __builtin_amdgcn_mfma_f32_32x32x16_bf16(w2, c2, accA, 0, 0, 0);
      accA = __builtin_amdgcn_mfma_f32_32x32x16_bf16(w4, c4, accA, 0, 0, 0);
      accA = __builtin_amdgcn_mfma_f32_32x32x16_bf16(w6, c6, accA, 0, 0, 0);
      accA = __builtin_amdgcn_mfma_f32_32x32x16_bf16(w8, c8, accA, 0, 0, 0);

      // chain B (odd ksteps + b1 column)
      bfrag w9 = *reinterpret_cast<const bfrag*>(wp + 9 * 64);
      bfrag w1 = *reinterpret_cast<const bfrag*>(wp + 1 * 64);
      bfrag w3 = *reinterpret_cast<const bfrag*>(wp + 3 * 64);
      bfrag w5 = *reinterpret_cast<const bfrag*>(wp + 5 * 64);
      bfrag w7 = *reinterpret_cast<const bfrag*>(wp + 7 * 64);
      f16v accB;
      accB = __builtin_amdgcn_mfma_f32_32x32x16_bf16(w9, cone, zerov, 0, 0, 0);
      accB = __builtin_amdgcn_mfma_f32_32x32x16_bf16(w1, c1, accB, 0, 0, 0);
      accB = __builtin_amdgcn_mfma_f32_32x32x16_bf16(w3, c3, accB, 0, 0, 0);
      accB = __builtin_amdgcn_mfma_f32_32x32x16_bf16(w5, c5, accB, 0, 0, 0);
      accB = __builtin_amdgcn_mfma_f32_32x32x16_bf16(w7, c7, accB, 0, 0, 0);

      // W2 quads from LDS (broadcast within each hi-group; conflict-free)
      const float* wq = &sW2[blk * 32 + 4 * hi];
      float4 q0 = *reinterpret_cast<const float4*>(wq);
      float4 q1 = *reinterpret_cast<const float4*>(wq + 8);
      float4 q2 = *reinterpret_cast<const float4*>(wq + 16);
      float4 q3 = *reinterpret_cast<const float4*>(wq + 24);

      // epilogue: h = accA+accB (b1 inside accB); 4 independent FMA chains
      p0 = fmaf(fmaxf(accA[0]  + accB[0],  0.f), q0.x, p0);
      p1 = fmaf(fmaxf(accA[1]  + accB[1],  0.f), q0.y, p1);
      p2 = fmaf(fmaxf(accA[2]  + accB[2],  0.f), q0.z, p2);
      p3 = fmaf(fmaxf(accA[3]  + accB[3],  0.f), q0.w, p3);
      p0 = fmaf(fmaxf(accA[4]  + accB[4],  0.f), q1.x, p0);
      p1 = fmaf(fmaxf(accA[5]  + accB[5],  0.f), q1.y, p1);
      p2 = fmaf(fmaxf(accA[6]  + accB[6],  0.f), q1.z, p2);
      p3 = fmaf(fmaxf(accA[7]  + accB[7],  0.f), q1.w, p3);
      p0 = fmaf(fmaxf(accA[8]  + accB[8],  0.f), q2.x, p0);
      p1 = fmaf(fmaxf(accA[9]  + accB[9],  0.f), q2.y, p1);
      p2 = fmaf(fmaxf(accA[10] + accB[10], 0.f), q2.z, p2);
      p3 = fmaf(fmaxf(accA[11] + accB[11], 0.f), q2.w, p3);
      p0 = fmaf(fmaxf(accA[12] + accB[12], 0.f), q3.x, p0);
      p1 = fmaf(fmaxf(accA[13] + accB[13], 0.f), q3.y, p1);
      p2 = fmaf(fmaxf(accA[14] + accB[14], 0.f), q3.z, p2);
      p3 = fmaf(fmaxf(accA[15] + accB[15], 0.f), q3.w, p3);
    }
    __builtin_amdgcn_s_setprio(0);

    float p = (p0 + p1) + (p2 + p3);
    p += __shfl_xor(p, 32);      // combine hi-half rows
    if (lane < 32)
      out[(size_t)tt * BM + lane] = 1.f / (1.f + __expf(-(p + bias2)));

    // rotate prefetched fragments
    c0 = n0; c1 = n1; c2 = n2; c3 = n3;
    c4 = n4; c5 = n5; c6 = n6; c7 = n7;
    ca = na; cb = nb;
  }
#undef GZ
}

extern "C" void kernel_launch(void* const* d_in, const int* in_sizes, int n_in,
                              void* d_out, int out_size, void* d_ws, size_t ws_size,
                              hipStream_t stream) {
  const float* z  = (const float*)d_in[0];
  const int*   ei = (const int*)d_in[1];
  const float* ea = (const float*)d_in[2];
  const float* W1 = (const float*)d_in[3];
  const float* b1 = (const float*)d_in[4];
  const float* W2 = (const float*)d_in[5];
  const float* b2 = (const float*)d_in[6];
  float* out = (float*)d_out;

  const size_t z16_bytes = (size_t)NN * ZD * sizeof(unsigned short);
  const size_t wt_bytes  = (size_t)WT_SHORTS * sizeof(unsigned short);

  if (ws_size >= z16_bytes + wt_bytes) {
    unsigned short* z16 = (unsigned short*)d_ws;
    unsigned short* WT  = z16 + (size_t)NN * ZD;
    const int n4 = NN * ZD / 4;
    zconv_kernel<<<(n4 + 255) / 256, 256, 0, stream>>>(z, z16, n4);
    wtab_kernel<<<(WT_SHORTS + 255) / 256, 256, 0, stream>>>(W1, b1, WT);
    fused_kernel<true><<<NBLK, THREADS, 0, stream>>>(
        z, z16, WT, ei, ea, W2, b2, out);
  } else {
    unsigned short* WT = (unsigned short*)d_ws;
    wtab_kernel<<<(WT_SHORTS + 255) / 256, 256, 0, stream>>>(W1, b1, WT);
    fused_kernel<false><<<NBLK, THREADS, 0, stream>>>(
        z, nullptr, WT, ei, ea, W2, b2, out);
  }
}